// Round 1
// baseline (2663.851 us; speedup 1.0000x reference)
//
#include <hip/hip_runtime.h>
#include <hip/hip_bf16.h>
#include <stdint.h>

typedef unsigned short u16;
typedef unsigned int   u32;
typedef __bf16 bf16_t;
typedef bf16_t bf16x8 __attribute__((ext_vector_type(8)));
typedef float  f32x4  __attribute__((ext_vector_type(4)));

#define NB     4096
#define LSEQ   28
#define DEMB   300
#define KREAL  8400      // 300*28
#define KPAD   8448      // 264*32
#define NPAIRS 8386560   // 4096*4095/2

__device__ __forceinline__ u16 f2bf(float f) {
  u32 u = __float_as_uint(f);
  u32 r = (u + 0x7fffu + ((u >> 16) & 1u)) >> 16;  // RNE
  return (u16)r;
}

// ---------------- weight transpose: in[O][I] -> out[I][O] ----------------
__global__ void transpose_k(const float* __restrict__ in, float* __restrict__ out,
                            int O, int I) {
  int idx = blockIdx.x * 256 + threadIdx.x;
  if (idx < O * I) {
    int j = idx / O, co = idx - j * O;
    out[idx] = in[co * I + j];
  }
}

// ---------------- embedding row scales: min(1, 1/(||row||+1e-7)) ----------------
__global__ __launch_bounds__(256) void scale_k(const float* __restrict__ emb,
                                               float* __restrict__ scale) {
  int r = blockIdx.x * 4 + (threadIdx.x >> 6);
  int lane = threadIdx.x & 63;
  const float* row = emb + (size_t)r * DEMB;
  float s = 0.f;
  for (int d = lane; d < DEMB; d += 64) { float v = row[d]; s += v * v; }
  for (int off = 32; off; off >>= 1) s += __shfl_xor(s, off, 64);
  if (lane == 0) scale[r] = fminf(1.f, 1.f / (sqrtf(s) + 1e-7f));
}

// ---------------- gather -> Xb bf16 [4096][8448], layout k = d*28 + l ----------------
__global__ __launch_bounds__(256) void embed_k(const int* __restrict__ x,
                                               const float* __restrict__ emb,
                                               const float* __restrict__ scale,
                                               u16* __restrict__ Xb) {
  __shared__ alignas(16) u16 es[KPAD];
  int b = blockIdx.x, tid = threadIdx.x;
  if (tid < KPAD - KREAL) es[KREAL + tid] = 0;  // zero K-pad
  const int* xr = x + b * LSEQ;
  for (int l = 0; l < LSEQ; ++l) {
    int v = xr[l];
    float s = scale[v];
    const float* er = emb + (size_t)v * DEMB;
    for (int d = tid; d < DEMB; d += 256) es[d * LSEQ + l] = f2bf(er[d] * s);
  }
  __syncthreads();
  uint4* dst = (uint4*)(Xb + (size_t)b * KPAD);
  const uint4* s4 = (const uint4*)es;
  for (int i = tid; i < KPAD / 8; i += 256) dst[i] = s4[i];
}

// ---------------- conv1: Xb(bf16) -> C1 fp32 [4096][300][13], stride2 pad1 ----------------
__global__ __launch_bounds__(320) void conv1_k(const u16* __restrict__ Xb,
                                               const float* __restrict__ w1t,  // [1500][300]
                                               const float* __restrict__ b1,
                                               float* __restrict__ C1) {
  __shared__ alignas(16) float xs[KREAL];
  int b = blockIdx.x, tid = threadIdx.x;
  const u32* row = (const u32*)(Xb + (size_t)b * KPAD);
  for (int i = tid; i < KREAL / 2; i += 320) {
    u32 u = row[i];
    xs[2 * i]     = __uint_as_float(u << 16);
    xs[2 * i + 1] = __uint_as_float(u & 0xffff0000u);
  }
  __syncthreads();
  if (tid < 300) {
    int co = tid;
    float acc[13];
    float bias = b1[co];
    #pragma unroll
    for (int t = 0; t < 13; ++t) acc[t] = bias;
    const float* wp = w1t + co;
    for (int ci = 0; ci < 300; ++ci) {
      float xv[28];
      const float4* xr4 = (const float4*)(xs + ci * 28);
      #pragma unroll
      for (int p = 0; p < 7; ++p) *(float4*)(xv + 4 * p) = xr4[p];
      #pragma unroll
      for (int k = 0; k < 5; ++k) {
        float wk = wp[(ci * 5 + k) * 300];
        #pragma unroll
        for (int t = 0; t < 13; ++t) {
          int pos = 2 * t + k - 1;
          if (pos >= 0 && pos < 28) acc[t] = fmaf(xv[pos], wk, acc[t]);
        }
      }
    }
    float* op = C1 + (size_t)b * 3900 + co * 13;
    #pragma unroll
    for (int t = 0; t < 13; ++t) op[t] = acc[t];
  }
}

// ---------------- BN stats: layout [4096][C][T]; writes folded A=g*inv, B=be-mean*A ----------------
__global__ __launch_bounds__(256) void stats_k(const float* __restrict__ src, int C, int T,
                                               const float* __restrict__ g,
                                               const float* __restrict__ be,
                                               float* __restrict__ bnA, float* __restrict__ bnB) {
  int c = blockIdx.x, tid = threadIdx.x;
  int N = NB * T;
  float s = 0.f, sq = 0.f;
  for (int i = tid; i < N; i += 256) {
    int b = i / T, t = i - b * T;
    float v = src[((size_t)b * C + c) * T + t];
    s += v; sq += v * v;
  }
  for (int off = 32; off; off >>= 1) { s += __shfl_xor(s, off, 64); sq += __shfl_xor(sq, off, 64); }
  __shared__ float l1[4], l2[4];
  int wave = tid >> 6, lane = tid & 63;
  if (lane == 0) { l1[wave] = s; l2[wave] = sq; }
  __syncthreads();
  if (tid == 0) {
    float S = l1[0] + l1[1] + l1[2] + l1[3];
    float Q = l2[0] + l2[1] + l2[2] + l2[3];
    float mean = S / N, var = Q / N - mean * mean;
    float inv = rsqrtf(var + 1e-5f);
    float A = g[c] * inv;
    bnA[c] = A; bnB[c] = be[c] - mean * A;
  }
}

// ---------------- conv2: BN1+relu applied at stage; C1 -> C2 [4096][600][5] ----------------
__global__ __launch_bounds__(320) void conv2_k(const float* __restrict__ C1,
                                               const float* __restrict__ bnA1,
                                               const float* __restrict__ bnB1,
                                               const float* __restrict__ w2t,  // [1500][600]
                                               const float* __restrict__ b2,
                                               float* __restrict__ C2) {
  __shared__ alignas(16) float ys[300 * 16];  // row stride 16 for aligned float4
  int b = blockIdx.x, tid = threadIdx.x;
  const float* src = C1 + (size_t)b * 3900;
  for (int i = tid; i < 3900; i += 320) {
    int ci = i / 13, t = i - ci * 13;
    ys[ci * 16 + t] = fmaxf(0.f, fmaf(src[i], bnA1[ci], bnB1[ci]));
  }
  __syncthreads();
  if (tid < 300) {
    int co = tid * 2;
    float acc0[5], acc1[5];
    float bias0 = b2[co], bias1 = b2[co + 1];
    #pragma unroll
    for (int t = 0; t < 5; ++t) { acc0[t] = bias0; acc1[t] = bias1; }
    const float* wp = w2t + co;
    for (int ci = 0; ci < 300; ++ci) {
      float xv[13];
      const float4* xr4 = (const float4*)(ys + ci * 16);
      #pragma unroll
      for (int p = 0; p < 3; ++p) *(float4*)(xv + 4 * p) = xr4[p];
      xv[12] = ys[ci * 16 + 12];
      #pragma unroll
      for (int k = 0; k < 5; ++k) {
        float2 wk = *(const float2*)(wp + (ci * 5 + k) * 600);
        #pragma unroll
        for (int t = 0; t < 5; ++t) {
          float xvv = xv[2 * t + k];
          acc0[t] = fmaf(xvv, wk.x, acc0[t]);
          acc1[t] = fmaf(xvv, wk.y, acc1[t]);
        }
      }
    }
    float* op = C2 + (size_t)b * 3000 + co * 5;
    #pragma unroll
    for (int t = 0; t < 5; ++t) { op[t] = acc0[t]; op[5 + t] = acc1[t]; }
  }
}

// ---------------- conv3 (+BN2+relu stage, tanh): 4 batches/block; writes h to d_out ----------------
__global__ __launch_bounds__(128) void conv3_k(const float* __restrict__ C2,
                                               const float* __restrict__ bnA2,
                                               const float* __restrict__ bnB2,
                                               const float* __restrict__ w3t,  // [3000][100]
                                               const float* __restrict__ b3,
                                               float* __restrict__ out) {
  __shared__ float ys[4][3000];
  int b0 = blockIdx.x * 4, tid = threadIdx.x;
  for (int bb = 0; bb < 4; ++bb) {
    const float* src = C2 + (size_t)(b0 + bb) * 3000;
    for (int i = tid; i < 3000; i += 128) {
      int ci = i / 5;
      ys[bb][i] = fmaxf(0.f, fmaf(src[i], bnA2[ci], bnB2[ci]));
    }
  }
  __syncthreads();
  if (tid < 100) {
    float a0 = b3[tid], a1 = a0, a2 = a0, a3 = a0;
    const float* wp = w3t + tid;
    for (int j = 0; j < 3000; ++j) {
      float w = wp[j * 100];
      a0 = fmaf(ys[0][j], w, a0);
      a1 = fmaf(ys[1][j], w, a1);
      a2 = fmaf(ys[2][j], w, a2);
      a3 = fmaf(ys[3][j], w, a3);
    }
    out[(size_t)b0 * 100 + tid]         = tanhf(a0);
    out[(size_t)(b0 + 1) * 100 + tid]   = tanhf(a1);
    out[(size_t)(b0 + 2) * 100 + tid]   = tanhf(a2);
    out[(size_t)(b0 + 3) * 100 + tid]   = tanhf(a3);
  }
}

// ---------------- normalize hidden rows -> Fn bf16 [4096][128] (zero-padded) ----------------
__global__ __launch_bounds__(64) void fn_k(const float* __restrict__ h, u16* __restrict__ Fn) {
  int b = blockIdx.x, lane = threadIdx.x;
  const float* row = h + (size_t)b * 100;
  float v0 = row[lane];
  float v1 = (lane + 64 < 100) ? row[lane + 64] : 0.f;
  float s = v0 * v0 + v1 * v1;
  for (int off = 32; off; off >>= 1) s += __shfl_xor(s, off, 64);
  float rn = rsqrtf(s);
  u16* orow = Fn + (size_t)b * 128;
  orow[lane]      = f2bf(v0 * rn);
  orow[lane + 64] = f2bf(v1 * rn);
}

// ---------------- upper-tri gram pairs via bf16 MFMA: out[p]=P_i . P_j, i<j ----------------
__global__ __launch_bounds__(256) void gram_k(const u16* __restrict__ P, int Kpad,
                                              float* __restrict__ outp) {
  __shared__ alignas(16) u16 As[128 * 32];
  __shared__ alignas(16) u16 Bs[128 * 32];
  const int T = 32;
  int q = blockIdx.x, ti = 0;
  while (q >= T - ti) { q -= T - ti; ++ti; }
  int tj = ti + q;

  int tid = threadIdx.x;
  int lane = tid & 63, wave = tid >> 6, wm = wave >> 1, wn = wave & 1;

  f32x4 acc[4][4];
  #pragma unroll
  for (int i = 0; i < 4; ++i)
    #pragma unroll
    for (int j = 0; j < 4; ++j) acc[i][j] = (f32x4){0.f, 0.f, 0.f, 0.f};

  const u16* PA = P + (size_t)ti * 128 * Kpad;
  const u16* PB = P + (size_t)tj * 128 * Kpad;

  int c0 = tid, c1 = tid + 256;
  int row0 = c0 >> 2, ch0 = c0 & 3;
  int row1 = c1 >> 2, ch1 = c1 & 3;

  for (int kk = 0; kk < Kpad; kk += 32) {
    uint4 a0 = *(const uint4*)(PA + (size_t)row0 * Kpad + kk + ch0 * 8);
    uint4 b0 = *(const uint4*)(PB + (size_t)row0 * Kpad + kk + ch0 * 8);
    uint4 a1 = *(const uint4*)(PA + (size_t)row1 * Kpad + kk + ch1 * 8);
    uint4 b1 = *(const uint4*)(PB + (size_t)row1 * Kpad + kk + ch1 * 8);
    *(uint4*)(As + c0 * 8) = a0;
    *(uint4*)(Bs + c0 * 8) = b0;
    *(uint4*)(As + c1 * 8) = a1;
    *(uint4*)(Bs + c1 * 8) = b1;
    __syncthreads();

    int koff = (lane >> 4) * 8;
    bf16x8 af[4], bf[4];
    #pragma unroll
    for (int m = 0; m < 4; ++m) {
      af[m] = *(const bf16x8*)(const void*)(As + (wm * 64 + m * 16 + (lane & 15)) * 32 + koff);
      bf[m] = *(const bf16x8*)(const void*)(Bs + (wn * 64 + m * 16 + (lane & 15)) * 32 + koff);
    }
    #pragma unroll
    for (int mi = 0; mi < 4; ++mi)
      #pragma unroll
      for (int mj = 0; mj < 4; ++mj)
        acc[mi][mj] = __builtin_amdgcn_mfma_f32_16x16x32_bf16(af[mi], bf[mj], acc[mi][mj], 0, 0, 0);
    __syncthreads();
  }

  // C/D layout (m89-verified): col = lane&15, row = (lane>>4)*4 + reg
  int rbase = ti * 128 + wm * 64 + ((lane >> 4) << 2);
  int cbase = tj * 128 + wn * 64 + (lane & 15);
  #pragma unroll
  for (int mi = 0; mi < 4; ++mi)
    #pragma unroll
    for (int mj = 0; mj < 4; ++mj) {
      int gj = cbase + mj * 16;
      #pragma unroll
      for (int r = 0; r < 4; ++r) {
        int gi = rbase + mi * 16 + r;
        if (gi < gj) {
          int p = gi * (NB - 1) - ((gi * (gi - 1)) >> 1) + (gj - gi - 1);
          outp[p] = acc[mi][mj][r];
        }
      }
    }
}

extern "C" void kernel_launch(void* const* d_in, const int* in_sizes, int n_in,
                              void* d_out, int out_size, void* d_ws, size_t ws_size,
                              hipStream_t stream) {
  const int*   x   = (const int*)d_in[0];
  const float* emb = (const float*)d_in[1];
  const float* w1  = (const float*)d_in[2];
  const float* b1  = (const float*)d_in[3];
  const float* w2  = (const float*)d_in[4];
  const float* b2  = (const float*)d_in[5];
  const float* w3  = (const float*)d_in[6];
  const float* b3  = (const float*)d_in[7];
  const float* g1  = (const float*)d_in[8];
  const float* be1 = (const float*)d_in[9];
  const float* g2  = (const float*)d_in[10];
  const float* be2 = (const float*)d_in[11];
  float* out = (float*)d_out;

  char* p = (char*)d_ws;
  auto alloc = [&](size_t bytes) { char* r = p; p += (bytes + 255) & ~(size_t)255; return r; };
  float* scale = (float*)alloc((size_t)32000 * 4);
  float* w1t   = (float*)alloc((size_t)1500 * 300 * 4);
  float* w2t   = (float*)alloc((size_t)1500 * 600 * 4);
  float* w3t   = (float*)alloc((size_t)3000 * 100 * 4);
  float* bnA1  = (float*)alloc(300 * 4);
  float* bnB1  = (float*)alloc(300 * 4);
  float* bnA2  = (float*)alloc(600 * 4);
  float* bnB2  = (float*)alloc(600 * 4);
  u16*   Fn    = (u16*)alloc((size_t)NB * 128 * 2);
  float* C1    = (float*)alloc((size_t)NB * 3900 * 4);
  u16*   Xb    = (u16*)alloc((size_t)NB * KPAD * 2);
  float* C2    = (float*)Xb;  // alias: conv2 runs after gram_k(Xb) completes (stream order)

  transpose_k<<<(300 * 1500 + 255) / 256, 256, 0, stream>>>(w1, w1t, 300, 1500);
  transpose_k<<<(600 * 1500 + 255) / 256, 256, 0, stream>>>(w2, w2t, 600, 1500);
  transpose_k<<<(100 * 3000 + 255) / 256, 256, 0, stream>>>(w3, w3t, 100, 3000);
  scale_k<<<32000 / 4, 256, 0, stream>>>(emb, scale);
  embed_k<<<NB, 256, 0, stream>>>(x, emb, scale, Xb);
  conv1_k<<<NB, 320, 0, stream>>>(Xb, w1t, b1, C1);
  gram_k<<<528, 256, 0, stream>>>(Xb, KPAD, out + 409600);           // input_pws
  stats_k<<<300, 256, 0, stream>>>(C1, 300, 13, g1, be1, bnA1, bnB1);
  conv2_k<<<NB, 320, 0, stream>>>(C1, bnA1, bnB1, w2t, b2, C2);
  stats_k<<<600, 256, 0, stream>>>(C2, 600, 5, g2, be2, bnA2, bnB2);
  conv3_k<<<NB / 4, 128, 0, stream>>>(C2, bnA2, bnB2, w3t, b3, out); // h
  fn_k<<<NB, 64, 0, stream>>>(out, Fn);
  gram_k<<<528, 256, 0, stream>>>(Fn, 128, out + 409600 + NPAIRS);   // hidden_pws
}

// Round 2
// 1144.943 us; speedup vs baseline: 2.3266x; 2.3266x over previous
//
#include <hip/hip_runtime.h>
#include <hip/hip_bf16.h>
#include <stdint.h>

typedef unsigned short u16;
typedef unsigned int   u32;
typedef __bf16 bf16_t;
typedef bf16_t bf16x8 __attribute__((ext_vector_type(8)));
typedef float  f32x4  __attribute__((ext_vector_type(4)));

#define NB     4096
#define LSEQ   28
#define DEMB   300
#define KREAL  8400      // 300*28
#define KPAD   8448      // 264*32
#define NPAIRS 8386560   // 4096*4095/2

#define KP1    1504      // conv1/conv2 K: 1500 padded to 47*32
#define KP3    3008      // conv3 K: 3000 padded to 94*32
#define N1TOT  53248     // 4096*13
#define N2TOT  20480     // 4096*5

__device__ __forceinline__ u16 f2bf(float f) {
  u32 u = __float_as_uint(f);
  u32 r = (u + 0x7fffu + ((u >> 16) & 1u)) >> 16;  // RNE
  return (u16)r;
}

// async global->LDS 16B copy; LDS dest = wave-uniform base + lane*16
__device__ __forceinline__ void cp16(const void* g, void* l) {
  __builtin_amdgcn_global_load_lds((const __attribute__((address_space(1))) void*)g,
                                   (__attribute__((address_space(3))) void*)l, 16, 0, 0);
}

// ---------------- pad+convert conv weight [M][Kreal] f32 -> [Mpad][Kpad] bf16 ----------------
__global__ void wconv_k(const float* __restrict__ w, u16* __restrict__ Aw,
                        int M, int Kreal, int Kpad, int tot) {
  int idx = blockIdx.x * 256 + threadIdx.x;
  if (idx >= tot) return;
  int m = idx / Kpad, k = idx - m * Kpad;
  Aw[idx] = (m < M && k < Kreal) ? f2bf(w[m * Kreal + k]) : (u16)0;
}

// ---------------- embedding row scales: min(1, 1/(||row||+1e-7)) ----------------
__global__ __launch_bounds__(256) void scale_k(const float* __restrict__ emb,
                                               float* __restrict__ scale) {
  int r = blockIdx.x * 4 + (threadIdx.x >> 6);
  int lane = threadIdx.x & 63;
  const float* row = emb + (size_t)r * DEMB;
  float s = 0.f;
  for (int d = lane; d < DEMB; d += 64) { float v = row[d]; s += v * v; }
  for (int off = 32; off; off >>= 1) s += __shfl_xor(s, off, 64);
  if (lane == 0) scale[r] = fminf(1.f, 1.f / (sqrtf(s) + 1e-7f));
}

// ---------------- gather -> Xb bf16 [4096][8448], layout k = d*28 + l ----------------
__global__ __launch_bounds__(256) void embed_k(const int* __restrict__ x,
                                               const float* __restrict__ emb,
                                               const float* __restrict__ scale,
                                               u16* __restrict__ Xb) {
  __shared__ alignas(16) u16 es[KPAD];
  int b = blockIdx.x, tid = threadIdx.x;
  if (tid < KPAD - KREAL) es[KREAL + tid] = 0;
  const int* xr = x + b * LSEQ;
  for (int l = 0; l < LSEQ; ++l) {
    int v = xr[l];
    float s = scale[v];
    const float* er = emb + (size_t)v * DEMB;
    for (int d = tid; d < DEMB; d += 256) es[d * LSEQ + l] = f2bf(er[d] * s);
  }
  __syncthreads();
  uint4* dst = (uint4*)(Xb + (size_t)b * KPAD);
  const uint4* s4 = (const uint4*)es;
  for (int i = tid; i < KPAD / 8; i += 256) dst[i] = s4[i];
}

// ---------------- im2col for conv1: Xb row b -> 13 rows of X1 [.][1504] ----------------
__global__ __launch_bounds__(256) void im2col1_k(const u16* __restrict__ Xb, int b0,
                                                 u16* __restrict__ X1) {
  __shared__ alignas(16) u16 xr[KPAD];
  int b = b0 + blockIdx.x, tid = threadIdx.x;
  const uint4* src = (const uint4*)(Xb + (size_t)b * KPAD);
  uint4* d4 = (uint4*)xr;
  for (int i = tid; i < KPAD / 8; i += 256) d4[i] = src[i];
  __syncthreads();
  for (int task = tid; task < 13 * 188; task += 256) {
    int t = task / 188, c = task - t * 188;
    uint4 v;
    u32 wv[4];
    #pragma unroll
    for (int jj = 0; jj < 4; ++jj) {
      u32 pk = 0;
      #pragma unroll
      for (int h = 0; h < 2; ++h) {
        int idx = c * 8 + jj * 2 + h;
        int ci = idx / 5, k = idx - ci * 5;
        int pos = 2 * t + k - 1;
        u16 e = 0;
        if (idx < 1500 && pos >= 0) e = xr[ci * 28 + pos];
        pk |= ((u32)e) << (16 * h);
      }
      wv[jj] = pk;
    }
    v.x = wv[0]; v.y = wv[1]; v.z = wv[2]; v.w = wv[3];
    *(uint4*)(X1 + ((size_t)(blockIdx.x * 13 + t)) * KP1 + c * 8) = v;
  }
}

// ---------------- BN stats over row-major [C][Ntot]: A=g*inv, B=be-mean*A ----------------
__global__ __launch_bounds__(256) void stats_k(const float* __restrict__ src, int Ntot,
                                               const float* __restrict__ g,
                                               const float* __restrict__ be,
                                               float* __restrict__ bnA, float* __restrict__ bnB) {
  int c = blockIdx.x, tid = threadIdx.x;
  const float* row = src + (size_t)c * Ntot;
  float s = 0.f, sq = 0.f;
  for (int i = tid; i < Ntot; i += 256) { float v = row[i]; s += v; sq += v * v; }
  for (int off = 32; off; off >>= 1) { s += __shfl_xor(s, off, 64); sq += __shfl_xor(sq, off, 64); }
  __shared__ float l1[4], l2[4];
  int wave = tid >> 6, lane = tid & 63;
  if (lane == 0) { l1[wave] = s; l2[wave] = sq; }
  __syncthreads();
  if (tid == 0) {
    float S = l1[0] + l1[1] + l1[2] + l1[3];
    float Q = l2[0] + l2[1] + l2[2] + l2[3];
    float mean = S / Ntot, var = Q / Ntot - mean * mean;
    float inv = rsqrtf(var + 1e-5f);
    float A = g[c] * inv;
    bnA[c] = A; bnB[c] = be[c] - mean * A;
  }
}

// ---------------- im2col for conv2: bn1+relu(C1) -> X2 [4096*5][1504] ----------------
__global__ __launch_bounds__(256) void im2col2_k(const float* __restrict__ C1,
                                                 const float* __restrict__ bnA,
                                                 const float* __restrict__ bnB,
                                                 u16* __restrict__ X2) {
  __shared__ u16 ys[3900];
  int b = blockIdx.x, tid = threadIdx.x;
  for (int i = tid; i < 3900; i += 256) {
    int ci = i / 13, t = i - ci * 13;
    float v = fmaxf(0.f, fmaf(C1[(size_t)ci * N1TOT + b * 13 + t], bnA[ci], bnB[ci]));
    ys[i] = f2bf(v);
  }
  __syncthreads();
  for (int task = tid; task < 5 * 188; task += 256) {
    int t = task / 188, c = task - t * 188;
    uint4 v;
    u32 wv[4];
    #pragma unroll
    for (int jj = 0; jj < 4; ++jj) {
      u32 pk = 0;
      #pragma unroll
      for (int h = 0; h < 2; ++h) {
        int idx = c * 8 + jj * 2 + h;
        int ci = idx / 5, k = idx - ci * 5;
        u16 e = (idx < 1500) ? ys[ci * 13 + 2 * t + k] : (u16)0;
        pk |= ((u32)e) << (16 * h);
      }
      wv[jj] = pk;
    }
    v.x = wv[0]; v.y = wv[1]; v.z = wv[2]; v.w = wv[3];
    *(uint4*)(X2 + ((size_t)b * 5 + t) * KP1 + c * 8) = v;
  }
}

// ---------------- im2col for conv3: bn2+relu(C2) -> X3 [4096][3008] ----------------
__global__ __launch_bounds__(128) void im2col3_k(const float* __restrict__ C2,
                                                 const float* __restrict__ bnA,
                                                 const float* __restrict__ bnB,
                                                 u16* __restrict__ X3) {
  int b = blockIdx.x, tid = threadIdx.x;
  for (int c = tid; c < 376; c += 128) {
    uint4 v;
    u32 wv[4];
    #pragma unroll
    for (int jj = 0; jj < 4; ++jj) {
      u32 pk = 0;
      #pragma unroll
      for (int h = 0; h < 2; ++h) {
        int idx = c * 8 + jj * 2 + h;
        u16 e = 0;
        if (idx < 3000) {
          int ci = idx / 5, k = idx - ci * 5;
          float val = fmaxf(0.f, fmaf(C2[(size_t)ci * N2TOT + b * 5 + k], bnA[ci], bnB[ci]));
          e = f2bf(val);
        }
        pk |= ((u32)e) << (16 * h);
      }
      wv[jj] = pk;
    }
    v.x = wv[0]; v.y = wv[1]; v.z = wv[2]; v.w = wv[3];
    *(uint4*)(X3 + (size_t)b * KP3 + c * 8) = v;
  }
}

// ---------------- GEMM C = A . B^T  (A:[Mpad][Kpad] bf16, B:[ntiles*128][Kpad] bf16) ----------------
// MODE 0: C[m][NtotC], cols offset n0, guard m<M.  MODE 1: C[n*100+m] = tanh(acc+bias[m]), m<M.
template <int MODE>
__global__ __launch_bounds__(256) void gemm_k(const u16* __restrict__ A,
                                              const u16* __restrict__ B,
                                              int Kpad, int M, int NtotC, int n0,
                                              float* __restrict__ C,
                                              const float* __restrict__ bias) {
  __shared__ alignas(16) u16 As[4096];
  __shared__ alignas(16) u16 Bs[4096];
  int tn = blockIdx.x, tm = blockIdx.y;
  int tid = threadIdx.x;
  int lane = tid & 63, wave = tid >> 6, wm = wave >> 1, wn = wave & 1;

  f32x4 acc[4][4];
  #pragma unroll
  for (int i = 0; i < 4; ++i)
    #pragma unroll
    for (int j = 0; j < 4; ++j) acc[i][j] = (f32x4){0.f, 0.f, 0.f, 0.f};

  const u16* PA = A + (size_t)(tm * 128) * Kpad;
  const u16* PB = B + (size_t)(tn * 128) * Kpad;
  int c0 = tid, c1 = tid + 256;
  const u16* gA0 = PA + (size_t)(c0 >> 2) * Kpad + (c0 & 3) * 8;
  const u16* gB0 = PB + (size_t)(c0 >> 2) * Kpad + (c0 & 3) * 8;
  const u16* gA1 = PA + (size_t)(c1 >> 2) * Kpad + (c1 & 3) * 8;
  const u16* gB1 = PB + (size_t)(c1 >> 2) * Kpad + (c1 & 3) * 8;
  u16* lA0 = As + wave * 512;
  u16* lB0 = Bs + wave * 512;
  u16* lA1 = As + 2048 + wave * 512;
  u16* lB1 = Bs + 2048 + wave * 512;

  for (int kk = 0; kk < Kpad; kk += 32) {
    cp16(gA0 + kk, lA0);
    cp16(gB0 + kk, lB0);
    cp16(gA1 + kk, lA1);
    cp16(gB1 + kk, lB1);
    __syncthreads();
    int koff = (lane >> 4) * 8;
    bf16x8 af[4], bfr[4];
    #pragma unroll
    for (int m = 0; m < 4; ++m) {
      af[m]  = *(const bf16x8*)(const void*)(As + (wm * 64 + m * 16 + (lane & 15)) * 32 + koff);
      bfr[m] = *(const bf16x8*)(const void*)(Bs + (wn * 64 + m * 16 + (lane & 15)) * 32 + koff);
    }
    #pragma unroll
    for (int mi = 0; mi < 4; ++mi)
      #pragma unroll
      for (int mj = 0; mj < 4; ++mj)
        acc[mi][mj] = __builtin_amdgcn_mfma_f32_16x16x32_bf16(af[mi], bfr[mj], acc[mi][mj], 0, 0, 0);
    __syncthreads();
  }

  int rb = wm * 64 + ((lane >> 4) << 2);
  int cb = wn * 64 + (lane & 15);
  if (MODE == 0) {
    #pragma unroll
    for (int mi = 0; mi < 4; ++mi)
      #pragma unroll
      for (int r = 0; r < 4; ++r) {
        int m = tm * 128 + rb + mi * 16 + r;
        if (m < M) {
          float* crow = C + (size_t)m * NtotC + n0 + tn * 128 + cb;
          #pragma unroll
          for (int mj = 0; mj < 4; ++mj) crow[mj * 16] = acc[mi][mj][r];
        }
      }
  } else {
    #pragma unroll
    for (int mi = 0; mi < 4; ++mi)
      #pragma unroll
      for (int r = 0; r < 4; ++r) {
        int m = rb + mi * 16 + r;
        if (m < M) {
          float bv = bias[m];
          #pragma unroll
          for (int mj = 0; mj < 4; ++mj) {
            int n = tn * 128 + cb + mj * 16;
            C[(size_t)n * 100 + m] = tanhf(acc[mi][mj][r] + bv);
          }
        }
      }
  }
}

// ---------------- normalize hidden rows -> Fn bf16 [4096][128] (zero-padded) ----------------
__global__ __launch_bounds__(64) void fn_k(const float* __restrict__ h, u16* __restrict__ Fn) {
  int b = blockIdx.x, lane = threadIdx.x;
  const float* row = h + (size_t)b * 100;
  float v0 = row[lane];
  float v1 = (lane + 64 < 100) ? row[lane + 64] : 0.f;
  float s = v0 * v0 + v1 * v1;
  for (int off = 32; off; off >>= 1) s += __shfl_xor(s, off, 64);
  float rn = rsqrtf(s);
  u16* orow = Fn + (size_t)b * 128;
  orow[lane]      = f2bf(v0 * rn);
  orow[lane + 64] = f2bf(v1 * rn);
}

// ---------------- upper-tri gram pairs via bf16 MFMA: out[p]=P_i . P_j, i<j ----------------
__global__ __launch_bounds__(256) void gram_k(const u16* __restrict__ P, int Kpad,
                                              float* __restrict__ outp) {
  __shared__ alignas(16) u16 As[4096];
  __shared__ alignas(16) u16 Bs[4096];
  const int T = 32;
  int q = blockIdx.x, ti = 0;
  while (q >= T - ti) { q -= T - ti; ++ti; }
  int tj = ti + q;

  int tid = threadIdx.x;
  int lane = tid & 63, wave = tid >> 6, wm = wave >> 1, wn = wave & 1;

  f32x4 acc[4][4];
  #pragma unroll
  for (int i = 0; i < 4; ++i)
    #pragma unroll
    for (int j = 0; j < 4; ++j) acc[i][j] = (f32x4){0.f, 0.f, 0.f, 0.f};

  const u16* PA = P + (size_t)ti * 128 * Kpad;
  const u16* PB = P + (size_t)tj * 128 * Kpad;
  int c0 = tid, c1 = tid + 256;
  const u16* gA0 = PA + (size_t)(c0 >> 2) * Kpad + (c0 & 3) * 8;
  const u16* gB0 = PB + (size_t)(c0 >> 2) * Kpad + (c0 & 3) * 8;
  const u16* gA1 = PA + (size_t)(c1 >> 2) * Kpad + (c1 & 3) * 8;
  const u16* gB1 = PB + (size_t)(c1 >> 2) * Kpad + (c1 & 3) * 8;
  u16* lA0 = As + wave * 512;
  u16* lB0 = Bs + wave * 512;
  u16* lA1 = As + 2048 + wave * 512;
  u16* lB1 = Bs + 2048 + wave * 512;

  for (int kk = 0; kk < Kpad; kk += 32) {
    cp16(gA0 + kk, lA0);
    cp16(gB0 + kk, lB0);
    cp16(gA1 + kk, lA1);
    cp16(gB1 + kk, lB1);
    __syncthreads();
    int koff = (lane >> 4) * 8;
    bf16x8 af[4], bfr[4];
    #pragma unroll
    for (int m = 0; m < 4; ++m) {
      af[m]  = *(const bf16x8*)(const void*)(As + (wm * 64 + m * 16 + (lane & 15)) * 32 + koff);
      bfr[m] = *(const bf16x8*)(const void*)(Bs + (wn * 64 + m * 16 + (lane & 15)) * 32 + koff);
    }
    #pragma unroll
    for (int mi = 0; mi < 4; ++mi)
      #pragma unroll
      for (int mj = 0; mj < 4; ++mj)
        acc[mi][mj] = __builtin_amdgcn_mfma_f32_16x16x32_bf16(af[mi], bfr[mj], acc[mi][mj], 0, 0, 0);
    __syncthreads();
  }

  // C/D layout (m89-verified): col = lane&15, row = (lane>>4)*4 + reg
  int rbase = ti * 128 + wm * 64 + ((lane >> 4) << 2);
  int cbase = tj * 128 + wn * 64 + (lane & 15);
  #pragma unroll
  for (int mi = 0; mi < 4; ++mi)
    #pragma unroll
    for (int mj = 0; mj < 4; ++mj) {
      int gj = cbase + mj * 16;
      #pragma unroll
      for (int r = 0; r < 4; ++r) {
        int gi = rbase + mi * 16 + r;
        if (gi < gj) {
          int p = gi * (NB - 1) - ((gi * (gi - 1)) >> 1) + (gj - gi - 1);
          outp[p] = acc[mi][mj][r];
        }
      }
    }
}

extern "C" void kernel_launch(void* const* d_in, const int* in_sizes, int n_in,
                              void* d_out, int out_size, void* d_ws, size_t ws_size,
                              hipStream_t stream) {
  const int*   x   = (const int*)d_in[0];
  const float* emb = (const float*)d_in[1];
  const float* w1  = (const float*)d_in[2];
  const float* w2  = (const float*)d_in[4];
  const float* w3  = (const float*)d_in[6];
  const float* b3  = (const float*)d_in[7];
  const float* g1  = (const float*)d_in[8];
  const float* be1 = (const float*)d_in[9];
  const float* g2  = (const float*)d_in[10];
  const float* be2 = (const float*)d_in[11];
  float* out = (float*)d_out;

  char* p = (char*)d_ws;
  auto alloc = [&](size_t bytes) { char* r = p; p += (bytes + 255) & ~(size_t)255; return r; };
  float* scale = (float*)alloc((size_t)32000 * 4);
  u16*   Aw1   = (u16*)alloc((size_t)384 * KP1 * 2);
  u16*   Aw2   = (u16*)alloc((size_t)640 * KP1 * 2);
  u16*   Aw3   = (u16*)alloc((size_t)128 * KP3 * 2);
  float* bnA1  = (float*)alloc(300 * 4);
  float* bnB1  = (float*)alloc(300 * 4);
  float* bnA2  = (float*)alloc(600 * 4);
  float* bnB2  = (float*)alloc(600 * 4);
  u16*   Fn    = (u16*)alloc((size_t)NB * 128 * 2);
  // Region A: Xb (69.2MB) -> later X2 (61.6MB)
  char*  regA  = alloc((size_t)NB * KPAD * 2);
  u16*   Xb    = (u16*)regA;
  u16*   X2    = (u16*)regA;
  // Region B: C1 (63.9MB) -> later X3 (24.6MB)
  char*  regB  = alloc((size_t)300 * N1TOT * 4);
  float* C1    = (float*)regB;
  u16*   X3    = (u16*)regB;
  // Region C: C2 (49.2MB) -> also hosts X1 quarter (40.0MB)
  char*  regC  = alloc((size_t)600 * N2TOT * 4);
  float* C2    = (float*)regC;
  u16*   X1    = (u16*)regC;

  wconv_k<<<(384 * KP1 + 255) / 256, 256, 0, stream>>>(w1, Aw1, 300, 1500, KP1, 384 * KP1);
  wconv_k<<<(640 * KP1 + 255) / 256, 256, 0, stream>>>(w2, Aw2, 600, 1500, KP1, 640 * KP1);
  wconv_k<<<(128 * KP3 + 255) / 256, 256, 0, stream>>>(w3, Aw3, 100, 3000, KP3, 128 * KP3);
  scale_k<<<32000 / 4, 256, 0, stream>>>(emb, scale);
  embed_k<<<NB, 256, 0, stream>>>(x, emb, scale, Xb);
  gram_k<<<528, 256, 0, stream>>>(Xb, KPAD, out + 409600);              // input_pws

  // conv1 as 4 quarter-GEMMs (X1 buffer reused; stream order serializes)
  for (int q = 0; q < 4; ++q) {
    im2col1_k<<<1024, 256, 0, stream>>>(Xb, q * 1024, X1);
    gemm_k<0><<<dim3(104, 3), 256, 0, stream>>>(Aw1, X1, KP1, 300, N1TOT, q * 13312, C1, nullptr);
  }
  stats_k<<<300, 256, 0, stream>>>(C1, N1TOT, g1, be1, bnA1, bnB1);
  im2col2_k<<<NB, 256, 0, stream>>>(C1, bnA1, bnB1, X2);                // X2 overwrites Xb (dead)
  gemm_k<0><<<dim3(160, 5), 256, 0, stream>>>(Aw2, X2, KP1, 600, N2TOT, 0, C2, nullptr);
  stats_k<<<600, 256, 0, stream>>>(C2, N2TOT, g2, be2, bnA2, bnB2);
  im2col3_k<<<NB, 128, 0, stream>>>(C2, bnA2, bnB2, X3);                // X3 overwrites C1 (dead)
  gemm_k<1><<<dim3(32, 1), 256, 0, stream>>>(Aw3, X3, KP3, 100, 0, 0, out, b3);  // h (+tanh)
  fn_k<<<NB, 64, 0, stream>>>(out, Fn);
  gram_k<<<528, 256, 0, stream>>>(Fn, 128, out + 409600 + NPAIRS);      // hidden_pws
}

// Round 3
// 1110.941 us; speedup vs baseline: 2.3978x; 1.0306x over previous
//
#include <hip/hip_runtime.h>
#include <hip/hip_bf16.h>
#include <stdint.h>

typedef unsigned short u16;
typedef unsigned int   u32;
typedef __bf16 bf16_t;
typedef bf16_t bf16x8 __attribute__((ext_vector_type(8)));
typedef float  f32x4  __attribute__((ext_vector_type(4)));

#define NB     4096
#define LSEQ   28
#define DEMB   300
#define KREAL  8400      // 300*28
#define KPAD   8448      // 264*32
#define NPAIRS 8386560   // 4096*4095/2

#define KP1    1504      // conv1/conv2 K: 1500 padded to 47*32
#define KP3    3008      // conv3 K: 3000 padded to 94*32
#define N1TOT  53248     // 4096*13
#define N2TOT  20480     // 4096*5

__device__ __forceinline__ u16 f2bf(float f) {
  u32 u = __float_as_uint(f);
  u32 r = (u + 0x7fffu + ((u >> 16) & 1u)) >> 16;  // RNE
  return (u16)r;
}

// async global->LDS 16B copy; LDS dest = wave-uniform base + lane*16
__device__ __forceinline__ void cp16(const void* g, void* l) {
  __builtin_amdgcn_global_load_lds((const __attribute__((address_space(1))) void*)g,
                                   (__attribute__((address_space(3))) void*)l, 16, 0, 0);
}

// ---------------- pad+convert conv weight [M][Kreal] f32 -> [Mpad][Kpad] bf16 ----------------
__global__ void wconv_k(const float* __restrict__ w, u16* __restrict__ Aw,
                        int M, int Kreal, int Kpad, int tot) {
  int idx = blockIdx.x * 256 + threadIdx.x;
  if (idx >= tot) return;
  int m = idx / Kpad, k = idx - m * Kpad;
  Aw[idx] = (m < M && k < Kreal) ? f2bf(w[m * Kreal + k]) : (u16)0;
}

// ---------------- embedding row scales: min(1, 1/(||row||+1e-7)) ----------------
__global__ __launch_bounds__(256) void scale_k(const float* __restrict__ emb,
                                               float* __restrict__ scale) {
  int r = blockIdx.x * 4 + (threadIdx.x >> 6);
  int lane = threadIdx.x & 63;
  const float* row = emb + (size_t)r * DEMB;
  float s = 0.f;
  for (int d = lane; d < DEMB; d += 64) { float v = row[d]; s += v * v; }
  for (int off = 32; off; off >>= 1) s += __shfl_xor(s, off, 64);
  if (lane == 0) scale[r] = fminf(1.f, 1.f / (sqrtf(s) + 1e-7f));
}

// ---------------- gather -> Xb bf16 [4096][8448], layout k = d*28 + l ----------------
__global__ __launch_bounds__(256) void embed_k(const int* __restrict__ x,
                                               const float* __restrict__ emb,
                                               const float* __restrict__ scale,
                                               u16* __restrict__ Xb) {
  __shared__ alignas(16) u16 es[KPAD];
  int b = blockIdx.x, tid = threadIdx.x;
  if (tid < KPAD - KREAL) es[KREAL + tid] = 0;
  const int* xr = x + b * LSEQ;
  for (int l = 0; l < LSEQ; ++l) {
    int v = xr[l];
    float s = scale[v];
    const float* er = emb + (size_t)v * DEMB;
    for (int d = tid; d < DEMB; d += 256) es[d * LSEQ + l] = f2bf(er[d] * s);
  }
  __syncthreads();
  uint4* dst = (uint4*)(Xb + (size_t)b * KPAD);
  const uint4* s4 = (const uint4*)es;
  for (int i = tid; i < KPAD / 8; i += 256) dst[i] = s4[i];
}

// ---------------- im2col for conv1: Xb row b -> 13 rows of X1 [.][1504] ----------------
__global__ __launch_bounds__(256) void im2col1_k(const u16* __restrict__ Xb, int b0,
                                                 u16* __restrict__ X1) {
  __shared__ alignas(16) u16 xr[KPAD];
  int b = b0 + blockIdx.x, tid = threadIdx.x;
  const uint4* src = (const uint4*)(Xb + (size_t)b * KPAD);
  uint4* d4 = (uint4*)xr;
  for (int i = tid; i < KPAD / 8; i += 256) d4[i] = src[i];
  __syncthreads();
  for (int task = tid; task < 13 * 188; task += 256) {
    int t = task / 188, c = task - t * 188;
    uint4 v;
    u32 wv[4];
    #pragma unroll
    for (int jj = 0; jj < 4; ++jj) {
      u32 pk = 0;
      #pragma unroll
      for (int h = 0; h < 2; ++h) {
        int idx = c * 8 + jj * 2 + h;
        int ci = idx / 5, k = idx - ci * 5;
        int pos = 2 * t + k - 1;
        u16 e = 0;
        if (idx < 1500 && pos >= 0) e = xr[ci * 28 + pos];
        pk |= ((u32)e) << (16 * h);
      }
      wv[jj] = pk;
    }
    v.x = wv[0]; v.y = wv[1]; v.z = wv[2]; v.w = wv[3];
    *(uint4*)(X1 + ((size_t)(blockIdx.x * 13 + t)) * KP1 + c * 8) = v;
  }
}

// ---------------- BN stats over row-major [C][Ntot]: A=g*inv, B=be-mean*A ----------------
__global__ __launch_bounds__(256) void stats_k(const float* __restrict__ src, int Ntot,
                                               const float* __restrict__ g,
                                               const float* __restrict__ be,
                                               float* __restrict__ bnA, float* __restrict__ bnB) {
  int c = blockIdx.x, tid = threadIdx.x;
  const float* row = src + (size_t)c * Ntot;
  float s = 0.f, sq = 0.f;
  for (int i = tid; i < Ntot; i += 256) { float v = row[i]; s += v; sq += v * v; }
  for (int off = 32; off; off >>= 1) { s += __shfl_xor(s, off, 64); sq += __shfl_xor(sq, off, 64); }
  __shared__ float l1[4], l2[4];
  int wave = tid >> 6, lane = tid & 63;
  if (lane == 0) { l1[wave] = s; l2[wave] = sq; }
  __syncthreads();
  if (tid == 0) {
    float S = l1[0] + l1[1] + l1[2] + l1[3];
    float Q = l2[0] + l2[1] + l2[2] + l2[3];
    float mean = S / Ntot, var = Q / Ntot - mean * mean;
    float inv = rsqrtf(var + 1e-5f);
    float A = g[c] * inv;
    bnA[c] = A; bnB[c] = be[c] - mean * A;
  }
}

// ---------------- im2col for conv2: bn1+relu(C1) -> X2 [4096*5][1504] ----------------
__global__ __launch_bounds__(256) void im2col2_k(const float* __restrict__ C1,
                                                 const float* __restrict__ bnA,
                                                 const float* __restrict__ bnB,
                                                 u16* __restrict__ X2) {
  __shared__ u16 ys[3900];
  int b = blockIdx.x, tid = threadIdx.x;
  for (int i = tid; i < 3900; i += 256) {
    int ci = i / 13, t = i - ci * 13;
    float v = fmaxf(0.f, fmaf(C1[(size_t)ci * N1TOT + b * 13 + t], bnA[ci], bnB[ci]));
    ys[i] = f2bf(v);
  }
  __syncthreads();
  for (int task = tid; task < 5 * 188; task += 256) {
    int t = task / 188, c = task - t * 188;
    uint4 v;
    u32 wv[4];
    #pragma unroll
    for (int jj = 0; jj < 4; ++jj) {
      u32 pk = 0;
      #pragma unroll
      for (int h = 0; h < 2; ++h) {
        int idx = c * 8 + jj * 2 + h;
        int ci = idx / 5, k = idx - ci * 5;
        u16 e = (idx < 1500) ? ys[ci * 13 + 2 * t + k] : (u16)0;
        pk |= ((u32)e) << (16 * h);
      }
      wv[jj] = pk;
    }
    v.x = wv[0]; v.y = wv[1]; v.z = wv[2]; v.w = wv[3];
    *(uint4*)(X2 + ((size_t)b * 5 + t) * KP1 + c * 8) = v;
  }
}

// ---------------- im2col for conv3: bn2+relu(C2) -> X3 [4096][3008] ----------------
__global__ __launch_bounds__(128) void im2col3_k(const float* __restrict__ C2,
                                                 const float* __restrict__ bnA,
                                                 const float* __restrict__ bnB,
                                                 u16* __restrict__ X3) {
  int b = blockIdx.x, tid = threadIdx.x;
  for (int c = tid; c < 376; c += 128) {
    uint4 v;
    u32 wv[4];
    #pragma unroll
    for (int jj = 0; jj < 4; ++jj) {
      u32 pk = 0;
      #pragma unroll
      for (int h = 0; h < 2; ++h) {
        int idx = c * 8 + jj * 2 + h;
        u16 e = 0;
        if (idx < 3000) {
          int ci = idx / 5, k = idx - ci * 5;
          float val = fmaxf(0.f, fmaf(C2[(size_t)ci * N2TOT + b * 5 + k], bnA[ci], bnB[ci]));
          e = f2bf(val);
        }
        pk |= ((u32)e) << (16 * h);
      }
      wv[jj] = pk;
    }
    v.x = wv[0]; v.y = wv[1]; v.z = wv[2]; v.w = wv[3];
    *(uint4*)(X3 + (size_t)b * KP3 + c * 8) = v;
  }
}

// ---------------- GEMM C = A . B^T  (A:[Mpad][Kpad] bf16, B:[ntiles*128][Kpad] bf16) ----------------
__global__ __launch_bounds__(256) void gemm_k(const u16* __restrict__ A,
                                              const u16* __restrict__ B,
                                              int Kpad, int M, int NtotC, int n0,
                                              float* __restrict__ C) {
  __shared__ alignas(16) u16 As[4096];
  __shared__ alignas(16) u16 Bs[4096];
  int tn = blockIdx.x, tm = blockIdx.y;
  int tid = threadIdx.x;
  int lane = tid & 63, wave = tid >> 6, wm = wave >> 1, wn = wave & 1;

  f32x4 acc[4][4];
  #pragma unroll
  for (int i = 0; i < 4; ++i)
    #pragma unroll
    for (int j = 0; j < 4; ++j) acc[i][j] = (f32x4){0.f, 0.f, 0.f, 0.f};

  const u16* PA = A + (size_t)(tm * 128) * Kpad;
  const u16* PB = B + (size_t)(tn * 128) * Kpad;
  int c0 = tid, c1 = tid + 256;
  const u16* gA0 = PA + (size_t)(c0 >> 2) * Kpad + (c0 & 3) * 8;
  const u16* gB0 = PB + (size_t)(c0 >> 2) * Kpad + (c0 & 3) * 8;
  const u16* gA1 = PA + (size_t)(c1 >> 2) * Kpad + (c1 & 3) * 8;
  const u16* gB1 = PB + (size_t)(c1 >> 2) * Kpad + (c1 & 3) * 8;
  u16* lA0 = As + wave * 512;
  u16* lB0 = Bs + wave * 512;
  u16* lA1 = As + 2048 + wave * 512;
  u16* lB1 = Bs + 2048 + wave * 512;

  for (int kk = 0; kk < Kpad; kk += 32) {
    cp16(gA0 + kk, lA0);
    cp16(gB0 + kk, lB0);
    cp16(gA1 + kk, lA1);
    cp16(gB1 + kk, lB1);
    __syncthreads();
    int koff = (lane >> 4) * 8;
    bf16x8 af[4], bfr[4];
    #pragma unroll
    for (int m = 0; m < 4; ++m) {
      af[m]  = *(const bf16x8*)(const void*)(As + (wm * 64 + m * 16 + (lane & 15)) * 32 + koff);
      bfr[m] = *(const bf16x8*)(const void*)(Bs + (wn * 64 + m * 16 + (lane & 15)) * 32 + koff);
    }
    #pragma unroll
    for (int mi = 0; mi < 4; ++mi)
      #pragma unroll
      for (int mj = 0; mj < 4; ++mj)
        acc[mi][mj] = __builtin_amdgcn_mfma_f32_16x16x32_bf16(af[mi], bfr[mj], acc[mi][mj], 0, 0, 0);
    __syncthreads();
  }

  int rb = wm * 64 + ((lane >> 4) << 2);
  int cb = wn * 64 + (lane & 15);
  #pragma unroll
  for (int mi = 0; mi < 4; ++mi)
    #pragma unroll
    for (int r = 0; r < 4; ++r) {
      int m = tm * 128 + rb + mi * 16 + r;
      if (m < M) {
        float* crow = C + (size_t)m * NtotC + n0 + tn * 128 + cb;
        #pragma unroll
        for (int mj = 0; mj < 4; ++mj) crow[mj * 16] = acc[mi][mj][r];
      }
    }
}

// ---------------- conv3 partial GEMM, split-K=3: Ph[(s*32+tn)][m*128+n] ----------------
__global__ __launch_bounds__(256) void gemm3p_k(const u16* __restrict__ A,
                                                const u16* __restrict__ B,
                                                float* __restrict__ Ph) {
  __shared__ alignas(16) u16 As[4096];
  __shared__ alignas(16) u16 Bs[4096];
  int tn = blockIdx.x, s = blockIdx.y;
  int kBeg = (s == 0) ? 0 : 1024 + (s - 1) * 992;
  int kEnd = (s == 0) ? 1024 : kBeg + 992;
  int tid = threadIdx.x;
  int lane = tid & 63, wave = tid >> 6, wm = wave >> 1, wn = wave & 1;

  f32x4 acc[4][4];
  #pragma unroll
  for (int i = 0; i < 4; ++i)
    #pragma unroll
    for (int j = 0; j < 4; ++j) acc[i][j] = (f32x4){0.f, 0.f, 0.f, 0.f};

  const u16* PA = A;
  const u16* PB = B + (size_t)(tn * 128) * KP3;
  int c0 = tid, c1 = tid + 256;
  const u16* gA0 = PA + (size_t)(c0 >> 2) * KP3 + (c0 & 3) * 8;
  const u16* gB0 = PB + (size_t)(c0 >> 2) * KP3 + (c0 & 3) * 8;
  const u16* gA1 = PA + (size_t)(c1 >> 2) * KP3 + (c1 & 3) * 8;
  const u16* gB1 = PB + (size_t)(c1 >> 2) * KP3 + (c1 & 3) * 8;
  u16* lA0 = As + wave * 512;
  u16* lB0 = Bs + wave * 512;
  u16* lA1 = As + 2048 + wave * 512;
  u16* lB1 = Bs + 2048 + wave * 512;

  for (int kk = kBeg; kk < kEnd; kk += 32) {
    cp16(gA0 + kk, lA0);
    cp16(gB0 + kk, lB0);
    cp16(gA1 + kk, lA1);
    cp16(gB1 + kk, lB1);
    __syncthreads();
    int koff = (lane >> 4) * 8;
    bf16x8 af[4], bfr[4];
    #pragma unroll
    for (int m = 0; m < 4; ++m) {
      af[m]  = *(const bf16x8*)(const void*)(As + (wm * 64 + m * 16 + (lane & 15)) * 32 + koff);
      bfr[m] = *(const bf16x8*)(const void*)(Bs + (wn * 64 + m * 16 + (lane & 15)) * 32 + koff);
    }
    #pragma unroll
    for (int mi = 0; mi < 4; ++mi)
      #pragma unroll
      for (int mj = 0; mj < 4; ++mj)
        acc[mi][mj] = __builtin_amdgcn_mfma_f32_16x16x32_bf16(af[mi], bfr[mj], acc[mi][mj], 0, 0, 0);
    __syncthreads();
  }

  float* po = Ph + ((size_t)(s * 32 + tn)) * 16384;
  int rb = wm * 64 + ((lane >> 4) << 2);
  int cb = wn * 64 + (lane & 15);
  #pragma unroll
  for (int mi = 0; mi < 4; ++mi)
    #pragma unroll
    for (int r = 0; r < 4; ++r) {
      int m = rb + mi * 16 + r;
      #pragma unroll
      for (int mj = 0; mj < 4; ++mj) po[(size_t)m * 128 + cb + mj * 16] = acc[mi][mj][r];
    }
}

// ---------------- finalize conv3: sum partials + bias, tanh, write h, normalize -> Fn ----------------
__global__ __launch_bounds__(64) void fin_k(const float* __restrict__ Ph,
                                            const float* __restrict__ b3,
                                            float* __restrict__ out, u16* __restrict__ Fn) {
  int b = blockIdx.x, lane = threadIdx.x;
  int tn = b >> 7, bl = b & 127;
  const float* base = Ph + (size_t)tn * 16384 + bl;
  float v0 = b3[lane];
  #pragma unroll
  for (int s = 0; s < 3; ++s) v0 += base[(size_t)s * 32 * 16384 + lane * 128];
  v0 = tanhf(v0);
  float v1 = 0.f;
  if (lane + 64 < 100) {
    v1 = b3[lane + 64];
    #pragma unroll
    for (int s = 0; s < 3; ++s) v1 += base[(size_t)s * 32 * 16384 + (lane + 64) * 128];
    v1 = tanhf(v1);
  }
  float s = v0 * v0 + v1 * v1;
  for (int off = 32; off; off >>= 1) s += __shfl_xor(s, off, 64);
  float rn = rsqrtf(s);
  out[(size_t)b * 100 + lane] = v0;
  if (lane + 64 < 100) out[(size_t)b * 100 + lane + 64] = v1;
  u16* orow = Fn + (size_t)b * 128;
  orow[lane]      = f2bf(v0 * rn);
  orow[lane + 64] = (lane + 64 < 100) ? f2bf(v1 * rn) : (u16)0;
}

// ---------------- input gram, split-K=2: full 128x128 partial tiles ----------------
__global__ __launch_bounds__(256) void gram_part_k(const u16* __restrict__ P,
                                                   float* __restrict__ Pout) {
  __shared__ alignas(16) u16 As[4096];
  __shared__ alignas(16) u16 Bs[4096];
  int tile = blockIdx.x;
  int q = tile, ti = 0;
  while (q >= 32 - ti) { q -= 32 - ti; ++ti; }
  int tj = ti + q;
  int s = blockIdx.y;
  int kBeg = s * (KPAD / 2), kEnd = kBeg + (KPAD / 2);

  int tid = threadIdx.x;
  int lane = tid & 63, wave = tid >> 6, wm = wave >> 1, wn = wave & 1;

  f32x4 acc[4][4];
  #pragma unroll
  for (int i = 0; i < 4; ++i)
    #pragma unroll
    for (int j = 0; j < 4; ++j) acc[i][j] = (f32x4){0.f, 0.f, 0.f, 0.f};

  const u16* PA = P + (size_t)ti * 128 * KPAD;
  const u16* PB = P + (size_t)tj * 128 * KPAD;
  int c0 = tid, c1 = tid + 256;
  const u16* gA0 = PA + (size_t)(c0 >> 2) * KPAD + (c0 & 3) * 8;
  const u16* gB0 = PB + (size_t)(c0 >> 2) * KPAD + (c0 & 3) * 8;
  const u16* gA1 = PA + (size_t)(c1 >> 2) * KPAD + (c1 & 3) * 8;
  const u16* gB1 = PB + (size_t)(c1 >> 2) * KPAD + (c1 & 3) * 8;
  u16* lA0 = As + wave * 512;
  u16* lB0 = Bs + wave * 512;
  u16* lA1 = As + 2048 + wave * 512;
  u16* lB1 = Bs + 2048 + wave * 512;

  for (int kk = kBeg; kk < kEnd; kk += 32) {
    cp16(gA0 + kk, lA0);
    cp16(gB0 + kk, lB0);
    cp16(gA1 + kk, lA1);
    cp16(gB1 + kk, lB1);
    __syncthreads();
    int koff = (lane >> 4) * 8;
    bf16x8 af[4], bfr[4];
    #pragma unroll
    for (int m = 0; m < 4; ++m) {
      af[m]  = *(const bf16x8*)(const void*)(As + (wm * 64 + m * 16 + (lane & 15)) * 32 + koff);
      bfr[m] = *(const bf16x8*)(const void*)(Bs + (wn * 64 + m * 16 + (lane & 15)) * 32 + koff);
    }
    #pragma unroll
    for (int mi = 0; mi < 4; ++mi)
      #pragma unroll
      for (int mj = 0; mj < 4; ++mj)
        acc[mi][mj] = __builtin_amdgcn_mfma_f32_16x16x32_bf16(af[mi], bfr[mj], acc[mi][mj], 0, 0, 0);
    __syncthreads();
  }

  float* po = Pout + ((size_t)(s * 528 + tile)) * 16384;
  int rb = wm * 64 + ((lane >> 4) << 2);
  int cb = wn * 64 + (lane & 15);
  #pragma unroll
  for (int mi = 0; mi < 4; ++mi)
    #pragma unroll
    for (int r = 0; r < 4; ++r) {
      int row = rb + mi * 16 + r;
      #pragma unroll
      for (int mj = 0; mj < 4; ++mj) po[(size_t)row * 128 + cb + mj * 16] = acc[mi][mj][r];
    }
}

// ---------------- reduce split-K partials -> triangular pair list ----------------
__global__ __launch_bounds__(256) void reduce_k(const float* __restrict__ P,
                                                float* __restrict__ outp) {
  int tile = blockIdx.x;
  int q = tile, ti = 0;
  while (q >= 32 - ti) { q -= 32 - ti; ++ti; }
  int tj = ti + q;
  const float4* p0 = (const float4*)(P + (size_t)tile * 16384);
  const float4* p1 = (const float4*)(P + (size_t)(528 + tile) * 16384);
  for (int e = threadIdx.x; e < 4096; e += 256) {
    float4 a = p0[e], bv = p1[e];
    int i = e >> 5;
    int j0 = (e & 31) * 4;
    int gi = ti * 128 + i;
    int gj = tj * 128 + j0;
    float v[4] = {a.x + bv.x, a.y + bv.y, a.z + bv.z, a.w + bv.w};
    #pragma unroll
    for (int u = 0; u < 4; ++u) {
      int gjj = gj + u;
      if (gi < gjj) {
        int pidx = gi * (NB - 1) - ((gi * (gi - 1)) >> 1) + (gjj - gi - 1);
        outp[pidx] = v[u];
      }
    }
  }
}

// ---------------- direct triangular gram (for hidden, K=128) ----------------
__global__ __launch_bounds__(256) void gram_k(const u16* __restrict__ P, int Kpad,
                                              float* __restrict__ outp) {
  __shared__ alignas(16) u16 As[4096];
  __shared__ alignas(16) u16 Bs[4096];
  int q = blockIdx.x, ti = 0;
  while (q >= 32 - ti) { q -= 32 - ti; ++ti; }
  int tj = ti + q;

  int tid = threadIdx.x;
  int lane = tid & 63, wave = tid >> 6, wm = wave >> 1, wn = wave & 1;

  f32x4 acc[4][4];
  #pragma unroll
  for (int i = 0; i < 4; ++i)
    #pragma unroll
    for (int j = 0; j < 4; ++j) acc[i][j] = (f32x4){0.f, 0.f, 0.f, 0.f};

  const u16* PA = P + (size_t)ti * 128 * Kpad;
  const u16* PB = P + (size_t)tj * 128 * Kpad;
  int c0 = tid, c1 = tid + 256;
  const u16* gA0 = PA + (size_t)(c0 >> 2) * Kpad + (c0 & 3) * 8;
  const u16* gB0 = PB + (size_t)(c0 >> 2) * Kpad + (c0 & 3) * 8;
  const u16* gA1 = PA + (size_t)(c1 >> 2) * Kpad + (c1 & 3) * 8;
  const u16* gB1 = PB + (size_t)(c1 >> 2) * Kpad + (c1 & 3) * 8;
  u16* lA0 = As + wave * 512;
  u16* lB0 = Bs + wave * 512;
  u16* lA1 = As + 2048 + wave * 512;
  u16* lB1 = Bs + 2048 + wave * 512;

  for (int kk = 0; kk < Kpad; kk += 32) {
    cp16(gA0 + kk, lA0);
    cp16(gB0 + kk, lB0);
    cp16(gA1 + kk, lA1);
    cp16(gB1 + kk, lB1);
    __syncthreads();
    int koff = (lane >> 4) * 8;
    bf16x8 af[4], bfr[4];
    #pragma unroll
    for (int m = 0; m < 4; ++m) {
      af[m]  = *(const bf16x8*)(const void*)(As + (wm * 64 + m * 16 + (lane & 15)) * 32 + koff);
      bfr[m] = *(const bf16x8*)(const void*)(Bs + (wn * 64 + m * 16 + (lane & 15)) * 32 + koff);
    }
    #pragma unroll
    for (int mi = 0; mi < 4; ++mi)
      #pragma unroll
      for (int mj = 0; mj < 4; ++mj)
        acc[mi][mj] = __builtin_amdgcn_mfma_f32_16x16x32_bf16(af[mi], bfr[mj], acc[mi][mj], 0, 0, 0);
    __syncthreads();
  }

  int rbase = ti * 128 + wm * 64 + ((lane >> 4) << 2);
  int cbase = tj * 128 + wn * 64 + (lane & 15);
  #pragma unroll
  for (int mi = 0; mi < 4; ++mi)
    #pragma unroll
    for (int mj = 0; mj < 4; ++mj) {
      int gj = cbase + mj * 16;
      #pragma unroll
      for (int r = 0; r < 4; ++r) {
        int gi = rbase + mi * 16 + r;
        if (gi < gj) {
          int p = gi * (NB - 1) - ((gi * (gi - 1)) >> 1) + (gj - gi - 1);
          outp[p] = acc[mi][mj][r];
        }
      }
    }
}

extern "C" void kernel_launch(void* const* d_in, const int* in_sizes, int n_in,
                              void* d_out, int out_size, void* d_ws, size_t ws_size,
                              hipStream_t stream) {
  const int*   x   = (const int*)d_in[0];
  const float* emb = (const float*)d_in[1];
  const float* w1  = (const float*)d_in[2];
  const float* w2  = (const float*)d_in[4];
  const float* w3  = (const float*)d_in[6];
  const float* b3  = (const float*)d_in[7];
  const float* g1  = (const float*)d_in[8];
  const float* be1 = (const float*)d_in[9];
  const float* g2  = (const float*)d_in[10];
  const float* be2 = (const float*)d_in[11];
  float* out = (float*)d_out;

  char* p = (char*)d_ws;
  auto alloc = [&](size_t bytes) { char* r = p; p += (bytes + 255) & ~(size_t)255; return r; };
  float* scale = (float*)alloc((size_t)32000 * 4);
  u16*   Aw1   = (u16*)alloc((size_t)384 * KP1 * 2);
  u16*   Aw2   = (u16*)alloc((size_t)640 * KP1 * 2);
  u16*   Aw3   = (u16*)alloc((size_t)128 * KP3 * 2);
  float* bnA1  = (float*)alloc(300 * 4);
  float* bnB1  = (float*)alloc(300 * 4);
  float* bnA2  = (float*)alloc(600 * 4);
  float* bnB2  = (float*)alloc(600 * 4);
  u16*   Fn    = (u16*)alloc((size_t)NB * 128 * 2);
  // Region A (69.2MB): Xb -> X2 (61.6MB; tail 7.6MB hosts Ph partials for conv3)
  char*  regA  = alloc((size_t)NB * KPAD * 2);
  u16*   Xb    = (u16*)regA;
  u16*   X2    = (u16*)regA;
  float* Ph    = (float*)(regA + 61603840);        // 6.29MB, after X2's 61.60MB
  // Region B (63.9MB): gram partial P half 0 -> C1 -> X3
  char*  regB  = alloc((size_t)300 * N1TOT * 4);
  float* C1    = (float*)regB;
  u16*   X3    = (u16*)regB;
  // Region C (49.2MB): gram partial P overflow -> C2 (also X1 quarter in fallback)
  char*  regC  = alloc((size_t)600 * N2TOT * 4);
  float* C2    = (float*)regC;
  float* Pg    = (float*)regB;                     // 69.2MB spans regB+regC (both dead then)
  // X1: full 160.2MB if ws allows, else quarter (40.0MB) in regC
  size_t used = (size_t)(p - (char*)d_ws);
  size_t x1full_bytes = (size_t)N1TOT * KP1 * 2;   // 160.2MB
  bool   full = (used + x1full_bytes) <= ws_size;
  u16*   X1   = full ? (u16*)alloc(x1full_bytes) : (u16*)regC;

  wconv_k<<<(384 * KP1 + 255) / 256, 256, 0, stream>>>(w1, Aw1, 300, 1500, KP1, 384 * KP1);
  wconv_k<<<(640 * KP1 + 255) / 256, 256, 0, stream>>>(w2, Aw2, 600, 1500, KP1, 640 * KP1);
  wconv_k<<<(128 * KP3 + 255) / 256, 256, 0, stream>>>(w3, Aw3, 100, 3000, KP3, 128 * KP3);
  scale_k<<<32000 / 4, 256, 0, stream>>>(emb, scale);
  embed_k<<<NB, 256, 0, stream>>>(x, emb, scale, Xb);

  // input_pws: split-K=2 gram (1056 blocks) + reduction
  gram_part_k<<<dim3(528, 2), 256, 0, stream>>>(Xb, Pg);
  reduce_k<<<528, 256, 0, stream>>>(Pg, out + 409600);

  // conv1 (Pg dead; C1 -> regB)
  if (full) {
    im2col1_k<<<NB, 256, 0, stream>>>(Xb, 0, X1);
    gemm_k<<<dim3(416, 3), 256, 0, stream>>>(Aw1, X1, KP1, 300, N1TOT, 0, C1);
  } else {
    for (int q = 0; q < 4; ++q) {
      im2col1_k<<<1024, 256, 0, stream>>>(Xb, q * 1024, X1);
      gemm_k<<<dim3(104, 3), 256, 0, stream>>>(Aw1, X1, KP1, 300, N1TOT, q * 13312, C1);
    }
  }
  stats_k<<<300, 256, 0, stream>>>(C1, N1TOT, g1, be1, bnA1, bnB1);
  im2col2_k<<<NB, 256, 0, stream>>>(C1, bnA1, bnB1, X2);                // X2 overwrites Xb (dead)
  gemm_k<<<dim3(160, 5), 256, 0, stream>>>(Aw2, X2, KP1, 600, N2TOT, 0, C2);
  stats_k<<<600, 256, 0, stream>>>(C2, N2TOT, g2, be2, bnA2, bnB2);
  im2col3_k<<<NB, 128, 0, stream>>>(C2, bnA2, bnB2, X3);                // X3 overwrites C1 (dead)
  gemm3p_k<<<dim3(32, 3), 256, 0, stream>>>(Aw3, X3, Ph);               // conv3 split-K=3 partials
  fin_k<<<NB, 64, 0, stream>>>(Ph, b3, out, Fn);                        // h + normalized Fn
  gram_k<<<528, 256, 0, stream>>>(Fn, 128, out + 409600 + NPAIRS);      // hidden_pws
}